// Round 13
// baseline (152.008 us; speedup 1.0000x reference)
//
#include <hip/hip_runtime.h>
#include <hip/hip_bf16.h>
#include <cmath>

#define NN 8192
#define FIN 256
#define FOUT 128
#define NCH 8
#define JC (NN / NCH)        // 1024 j per chunk
#define WPC (JC / 64)        // 16 windows (of 64 j) per chunk
#define MPITCH 17            // LDS mask row pitch (u64)
#define LOG2E 1.44269504f

typedef short short8 __attribute__((ext_vector_type(8)));
typedef float f32x4 __attribute__((ext_vector_type(4)));
typedef float f32x16 __attribute__((ext_vector_type(16)));
typedef unsigned long long u64;

static __device__ __forceinline__ unsigned short f2bf(float f) {
    unsigned u = __float_as_uint(f);
    u += 0x7fffu + ((u >> 16) & 1u);
    return (unsigned short)(u >> 16);
}

static __device__ __forceinline__ unsigned cvtpk(float lo, float hi) {
    unsigned r;
    asm("v_cvt_pk_bf16_f32 %0, %1, %2" : "=v"(r) : "v"(lo), "v"(hi));
    return r;
}

// ---------------------------------------------------------------------------
// Pass A: h = input @ W^T + Wb (bf16 MFMA). Writes hT4 in 16x16x32 A-frag
// order so pass_b A-frag loads are 64-lane-contiguous 1KB.
// s = h·a1 * log2e,  t = (h·a2 + ab) * log2e  (exp -> exp2 domain).
// ---------------------------------------------------------------------------
__global__ __launch_bounds__(256, 2)
void gat_pass_a(const float* __restrict__ input, const float* __restrict__ W,
                const float* __restrict__ Wb, const float* __restrict__ aw,
                const float* __restrict__ ab, unsigned short* __restrict__ hT4,
                float* __restrict__ s_out, float* __restrict__ t_out) {
    const int tid = threadIdx.x;
    const int w = tid >> 6, l = tid & 63;
    const int l5 = l >> 5, l31 = l & 31;
    const int nt = w >> 1, mh = w & 1;
    const int bx = blockIdx.x;
    const int i = bx * 64 + nt * 32 + l31;

    f32x16 acc0 = {}; f32x16 acc1 = {};
    #pragma unroll
    for (int ks = 0; ks < FIN / 16; ++ks) {
        const int c0 = ks * 16 + l5 * 8;
        const float4 b0 = *(const float4*)(input + (size_t)i * FIN + c0);
        const float4 b1 = *(const float4*)(input + (size_t)i * FIN + c0 + 4);
        short8 bf;
        bf[0]=(short)f2bf(b0.x); bf[1]=(short)f2bf(b0.y); bf[2]=(short)f2bf(b0.z); bf[3]=(short)f2bf(b0.w);
        bf[4]=(short)f2bf(b1.x); bf[5]=(short)f2bf(b1.y); bf[6]=(short)f2bf(b1.z); bf[7]=(short)f2bf(b1.w);
        {
            const int kcol = l31 + 32 * (2 * mh + 0);
            const float4 a0 = *(const float4*)(W + (size_t)kcol * FIN + c0);
            const float4 a1 = *(const float4*)(W + (size_t)kcol * FIN + c0 + 4);
            short8 af;
            af[0]=(short)f2bf(a0.x); af[1]=(short)f2bf(a0.y); af[2]=(short)f2bf(a0.z); af[3]=(short)f2bf(a0.w);
            af[4]=(short)f2bf(a1.x); af[5]=(short)f2bf(a1.y); af[6]=(short)f2bf(a1.z); af[7]=(short)f2bf(a1.w);
            acc0 = __builtin_amdgcn_mfma_f32_32x32x16_bf16(af, bf, acc0, 0, 0, 0);
        }
        {
            const int kcol = l31 + 32 * (2 * mh + 1);
            const float4 a0 = *(const float4*)(W + (size_t)kcol * FIN + c0);
            const float4 a1 = *(const float4*)(W + (size_t)kcol * FIN + c0 + 4);
            short8 af;
            af[0]=(short)f2bf(a0.x); af[1]=(short)f2bf(a0.y); af[2]=(short)f2bf(a0.z); af[3]=(short)f2bf(a0.w);
            af[4]=(short)f2bf(a1.x); af[5]=(short)f2bf(a1.y); af[6]=(short)f2bf(a1.z); af[7]=(short)f2bf(a1.w);
            acc1 = __builtin_amdgcn_mfma_f32_32x32x16_bf16(af, bf, acc1, 0, 0, 0);
        }
    }
    __shared__ float sred[4][32];
    __shared__ float tred[4][32];
    float sacc = 0.f, tacc = 0.f;
    const int jt = bx * 2 + nt;                     // j-tile (32-wide)
    const int lane_half = 16 * (l31 >> 3);
    const int e4 = l31 & 7;
    #pragma unroll
    for (int m = 0; m < 2; ++m) {
        #pragma unroll
        for (int r = 0; r < 16; ++r) {
            const int kcol = 32 * (2 * mh + m) + 4 * l5 + (r & 3) + 8 * (r >> 2);
            const float hv = (m ? acc1[r] : acc0[r]) + Wb[kcol];
            const int lane4 = (kcol & 15) + lane_half;
            hT4[(size_t)(jt * 8 + (kcol >> 4)) * 512 + lane4 * 8 + e4] = f2bf(hv);
            sacc += hv * aw[kcol];
            tacc += hv * aw[FOUT + kcol];
        }
    }
    sacc += __shfl_xor(sacc, 32);
    tacc += __shfl_xor(tacc, 32);
    if (l < 32) { sred[w][l] = sacc; tred[w][l] = tacc; }
    __syncthreads();
    if (mh == 0 && l < 32) {
        s_out[i] = (sred[w][l] + sred[w + 1][l]) * LOG2E;
        t_out[i] = (tred[w][l] + tred[w + 1][l] + ab[0]) * LOG2E;
    }
}

// ---------------------------------------------------------------------------
// Pass B (FUSED adj streaming + compute):
// Stage phase (per block, 64 rows x 1024-j chunk): each thread reads 1KB of
// adj CONTIGUOUSLY (its own row / col-quarter, 4 x 64-col units of 16 int4),
// bit-packs in registers (no ballots), writes 4 u64 words to LDS. Also stages
// the chunk's t (4KB) into LDS. ONE barrier.
// Compute phase (barrier-free): 16x16x32 MFMA, wave owns 16 rows x 128 f;
// masks+t from LDS; denominator via 9th MFMA with all-ones A-frag.
// Inter-block TLP (4 blocks/CU) overlaps stage-HBM with compute.
// ---------------------------------------------------------------------------
__global__ __launch_bounds__(256, 4)
void gat_pass_b(const int* __restrict__ adj, const unsigned short* __restrict__ hT4,
                const float* __restrict__ s_in, const float* __restrict__ t_in,
                float* __restrict__ numw, float* __restrict__ dpart) {
    __shared__ u64 mlds[64 * MPITCH];        // 8.5 KB
    __shared__ float tlds[JC];               // 4 KB
    const int tid = threadIdx.x;
    const int wv = tid >> 6, l = tid & 63;
    const int li = l & 15;                   // i within wave tile
    const int kq = l >> 4;                   // k-quarter (0..3)
    const int i0 = blockIdx.x * 64;
    const int chunk = blockIdx.y;
    const int jb = chunk * JC;

    // ---- stage t (coalesced) ----
    *(float4*)&tlds[tid * 4] = *(const float4*)(t_in + jb + tid * 4);

    // ---- stage adj -> masks: thread owns row i0+(tid>>2), cols (tid&3)*256 ----
    {
        const int srow = i0 + (tid >> 2);
        const int4* ap = (const int4*)(adj + (size_t)srow * NN + jb + (tid & 3) * 256);
        u64* mrow = mlds + (tid >> 2) * MPITCH + (tid & 3) * 4;
        #pragma unroll
        for (int u = 0; u < 4; ++u) {
            u64 m = 0;
            #pragma unroll
            for (int q = 0; q < 16; ++q) {
                const int4 v = ap[u * 16 + q];
                m |= (u64)(v.x > 0) << (q * 4 + 0);
                m |= (u64)(v.y > 0) << (q * 4 + 1);
                m |= (u64)(v.z > 0) << (q * 4 + 2);
                m |= (u64)(v.w > 0) << (q * 4 + 3);
            }
            mrow[u] = m;
        }
    }
    const int lrow = wv * 16 + li;
    const float si = s_in[i0 + lrow];
    __syncthreads();

    f32x4 acc0 = {}, acc1 = {}, acc2 = {}, acc3 = {};
    f32x4 acc4 = {}, acc5 = {}, acc6 = {}, acc7 = {};
    f32x4 accd = {};
    short8 ones;
    #pragma unroll
    for (int e = 0; e < 8; ++e) ones[e] = (short)0x3F80;   // bf16 1.0

    for (int win = 0; win < WPC; ++win) {
        const u64 mword = mlds[lrow * MPITCH + win];
        const int jw = jb + win * 64;
        #pragma unroll
        for (int kk = 0; kk < 2; ++kk) {
            const int jt = (jw + kk * 32) >> 5;
            const unsigned short* hp = hT4 + (size_t)jt * 4096 + (size_t)l * 8;
            const short8 af0 = *(const short8*)(hp);
            const short8 af1 = *(const short8*)(hp + 512);
            const short8 af2 = *(const short8*)(hp + 1024);
            const short8 af3 = *(const short8*)(hp + 1536);
            const short8 af4 = *(const short8*)(hp + 2048);
            const short8 af5 = *(const short8*)(hp + 2560);
            const short8 af6 = *(const short8*)(hp + 3072);
            const short8 af7 = *(const short8*)(hp + 3584);
            const int tix = win * 64 + kk * 32 + kq * 8;
            const float4 t0 = *(const float4*)&tlds[tix];
            const float4 t1 = *(const float4*)&tlds[tix + 4];
            const unsigned mk = (unsigned)(mword >> (kk * 32 + kq * 8)) & 0xffu;

            float x, p0, p1, p2, p3, p4, p5, p6, p7;
            x = si + t0.x; x = fmaxf(x, 0.2f * x); p0 = exp2f(x);
            p0 = (mk & 1u)   ? p0 : 0.f;
            x = si + t0.y; x = fmaxf(x, 0.2f * x); p1 = exp2f(x);
            p1 = (mk & 2u)   ? p1 : 0.f;
            x = si + t0.z; x = fmaxf(x, 0.2f * x); p2 = exp2f(x);
            p2 = (mk & 4u)   ? p2 : 0.f;
            x = si + t0.w; x = fmaxf(x, 0.2f * x); p3 = exp2f(x);
            p3 = (mk & 8u)   ? p3 : 0.f;
            x = si + t1.x; x = fmaxf(x, 0.2f * x); p4 = exp2f(x);
            p4 = (mk & 16u)  ? p4 : 0.f;
            x = si + t1.y; x = fmaxf(x, 0.2f * x); p5 = exp2f(x);
            p5 = (mk & 32u)  ? p5 : 0.f;
            x = si + t1.z; x = fmaxf(x, 0.2f * x); p6 = exp2f(x);
            p6 = (mk & 64u)  ? p6 : 0.f;
            x = si + t1.w; x = fmaxf(x, 0.2f * x); p7 = exp2f(x);
            p7 = (mk & 128u) ? p7 : 0.f;

            union { int4 i4; short8 s8; } bu;
            bu.i4.x = (int)cvtpk(p0, p1);
            bu.i4.y = (int)cvtpk(p2, p3);
            bu.i4.z = (int)cvtpk(p4, p5);
            bu.i4.w = (int)cvtpk(p6, p7);
            const short8 bf = bu.s8;

            acc0 = __builtin_amdgcn_mfma_f32_16x16x32_bf16(af0, bf, acc0, 0, 0, 0);
            acc1 = __builtin_amdgcn_mfma_f32_16x16x32_bf16(af1, bf, acc1, 0, 0, 0);
            acc2 = __builtin_amdgcn_mfma_f32_16x16x32_bf16(af2, bf, acc2, 0, 0, 0);
            acc3 = __builtin_amdgcn_mfma_f32_16x16x32_bf16(af3, bf, acc3, 0, 0, 0);
            acc4 = __builtin_amdgcn_mfma_f32_16x16x32_bf16(af4, bf, acc4, 0, 0, 0);
            acc5 = __builtin_amdgcn_mfma_f32_16x16x32_bf16(af5, bf, acc5, 0, 0, 0);
            acc6 = __builtin_amdgcn_mfma_f32_16x16x32_bf16(af6, bf, acc6, 0, 0, 0);
            acc7 = __builtin_amdgcn_mfma_f32_16x16x32_bf16(af7, bf, acc7, 0, 0, 0);
            accd = __builtin_amdgcn_mfma_f32_16x16x32_bf16(ones, bf, accd, 0, 0, 0);
        }
    }

    // ---- epilogue: direct coalesced stores (no reduction, no barrier) ----
    float* nb = numw + (size_t)chunk * FOUT * NN;
    const int irow = i0 + lrow;
    #pragma unroll
    for (int r = 0; r < 4; ++r) {
        const int fr = kq * 4 + r;
        nb[(size_t)(fr      ) * NN + irow] = acc0[r];
        nb[(size_t)(fr + 16 ) * NN + irow] = acc1[r];
        nb[(size_t)(fr + 32 ) * NN + irow] = acc2[r];
        nb[(size_t)(fr + 48 ) * NN + irow] = acc3[r];
        nb[(size_t)(fr + 64 ) * NN + irow] = acc4[r];
        nb[(size_t)(fr + 80 ) * NN + irow] = acc5[r];
        nb[(size_t)(fr + 96 ) * NN + irow] = acc6[r];
        nb[(size_t)(fr + 112) * NN + irow] = acc7[r];
    }
    if (l < 16) dpart[(size_t)chunk * NN + i0 + wv * 16 + l] = accd[0];
}

// ---------------------------------------------------------------------------
// Pass C: out[i][f] = elu( sum_c numw[c][f][i] / sum_c dpart[c][i] )
// ---------------------------------------------------------------------------
__global__ __launch_bounds__(256)
void gat_reduce(const float* __restrict__ numw, const float* __restrict__ dpart,
                float* __restrict__ out, int nchunk) {
    __shared__ float tile[FOUT * 33];
    __shared__ float dent[32];
    const int t = threadIdx.x;
    const int i0 = blockIdx.x * 32;
    if (t < 32) {
        float d = 0.f;
        for (int c = 0; c < nchunk; ++c) d += dpart[(size_t)c * NN + i0 + t];
        dent[t] = d;
    }
    __syncthreads();
    #pragma unroll
    for (int e = 0; e < 4; ++e) {
        const int f = e * 32 + (t >> 3);
        const int io = (t & 7) * 4;
        float4 s = {0.f, 0.f, 0.f, 0.f};
        for (int c = 0; c < nchunk; ++c) {
            const float4 v = *(const float4*)(numw + ((size_t)c * FOUT + f) * NN + i0 + io);
            s.x += v.x; s.y += v.y; s.z += v.z; s.w += v.w;
        }
        float v;
        v = s.x / dent[io + 0]; tile[f * 33 + io + 0] = (v > 0.f) ? v : expm1f(v);
        v = s.y / dent[io + 1]; tile[f * 33 + io + 1] = (v > 0.f) ? v : expm1f(v);
        v = s.z / dent[io + 2]; tile[f * 33 + io + 2] = (v > 0.f) ? v : expm1f(v);
        v = s.w / dent[io + 3]; tile[f * 33 + io + 3] = (v > 0.f) ? v : expm1f(v);
    }
    __syncthreads();
    #pragma unroll
    for (int e = 0; e < 4; ++e) {
        const int row = (t >> 5) * 4 + e;
        const int fo = (t & 31) * 4;
        const float4 v = { tile[(fo + 0) * 33 + row], tile[(fo + 1) * 33 + row],
                           tile[(fo + 2) * 33 + row], tile[(fo + 3) * 33 + row] };
        *(float4*)(out + (size_t)(i0 + row) * FOUT + fo) = v;
    }
}

// ---------------------------------------------------------------------------
extern "C" void kernel_launch(void* const* d_in, const int* in_sizes, int n_in,
                              void* d_out, int out_size, void* d_ws, size_t ws_size,
                              hipStream_t stream) {
    const float* input = (const float*)d_in[0];
    const int*   adj   = (const int*)d_in[1];
    const float* Ww    = (const float*)d_in[2];
    const float* Wb    = (const float*)d_in[3];
    const float* aw    = (const float*)d_in[4];
    const float* ab    = (const float*)d_in[5];
    float* out = (float*)d_out;

    char* ws = (char*)d_ws;
    unsigned short* hT4 = (unsigned short*)ws;               // 2 MB
    float* s_buf = (float*)(ws + (size_t)FOUT * NN * 2);     // 32 KB
    float* t_buf = s_buf + NN;                               // 32 KB
    float* dpart = t_buf + NN;                               // NCH*32 KB
    float* numw = dpart + (size_t)NCH * NN;                  // NCH*4 MB

    gat_pass_a<<<dim3(NN / 64), 256, 0, stream>>>(input, Ww, Wb, aw, ab, hT4, s_buf, t_buf);
    gat_pass_b<<<dim3(NN / 64, NCH), 256, 0, stream>>>(adj, hT4, s_buf, t_buf, numw, dpart);
    gat_reduce<<<dim3(NN / 32), 256, 0, stream>>>(numw, dpart, out, NCH);
}

// Round 14
// 124.283 us; speedup vs baseline: 1.2231x; 1.2231x over previous
//
#include <hip/hip_runtime.h>
#include <hip/hip_bf16.h>
#include <cmath>

#define NN 8192
#define FIN 256
#define FOUT 128
#define NCH 8
#define JC (NN / NCH)        // 1024 j per chunk
#define WPC (JC / 64)        // 16 windows (of 64 j) per chunk
#define LOG2E 1.44269504f

typedef short short8 __attribute__((ext_vector_type(8)));
typedef float f32x4 __attribute__((ext_vector_type(4)));
typedef float f32x16 __attribute__((ext_vector_type(16)));
typedef unsigned long long u64;

static __device__ __forceinline__ unsigned short f2bf(float f) {
    unsigned u = __float_as_uint(f);
    u += 0x7fffu + ((u >> 16) & 1u);
    return (unsigned short)(u >> 16);
}

static __device__ __forceinline__ unsigned cvtpk(float lo, float hi) {
    unsigned r;
    asm("v_cvt_pk_bf16_f32 %0, %1, %2" : "=v"(r) : "v"(lo), "v"(hi));
    return r;
}

// ---------------------------------------------------------------------------
// Stage kernel (heterogeneous): blocks 0..127 run pass_a (h-projection, s, t),
// blocks 128..4223 run compress (adj -> bm3, row-dense streaming). pass_a
// blocks dispatch FIRST so their MFMA/VALU work overlaps the HBM stream.
// compress: thread reads 256B contiguous; wave covers dense 16KB; block 64KB.
// bm3 layout [chunk][row][16 u64], plain bit order (bit n = col win*64+n).
// ---------------------------------------------------------------------------
__global__ __launch_bounds__(256, 2)
void gat_stage(const float* __restrict__ input, const int* __restrict__ adj,
               const float* __restrict__ W, const float* __restrict__ Wb,
               const float* __restrict__ aw, const float* __restrict__ ab,
               unsigned short* __restrict__ hT4, float* __restrict__ s_out,
               float* __restrict__ t_out, u64* __restrict__ bm3) {
    __shared__ float sred[4][32];
    __shared__ float tred[4][32];
    const int tid = threadIdx.x;

    if (blockIdx.x >= 128) {
        // ------------------- compress body -------------------
        const int row = (blockIdx.x - 128) * 2 + (tid >> 7);
        const int wing = tid & 127;
        const int4* p = (const int4*)(adj + (size_t)row * NN + wing * 64);
        u64 m = 0;
        #pragma unroll
        for (int q = 0; q < 16; ++q) {
            const int4 v = p[q];
            m |= (u64)(v.x > 0) << (q * 4 + 0);
            m |= (u64)(v.y > 0) << (q * 4 + 1);
            m |= (u64)(v.z > 0) << (q * 4 + 2);
            m |= (u64)(v.w > 0) << (q * 4 + 3);
        }
        const int ch = wing >> 4, winc = wing & 15;
        bm3[((size_t)ch * NN + row) * 16 + winc] = m;
        return;
    }

    // ------------------- pass_a body -------------------
    const int w = tid >> 6, l = tid & 63;
    const int l5 = l >> 5, l31 = l & 31;
    const int nt = w >> 1, mh = w & 1;
    const int bx = blockIdx.x;
    const int i = bx * 64 + nt * 32 + l31;

    f32x16 acc0 = {}; f32x16 acc1 = {};
    #pragma unroll
    for (int ks = 0; ks < FIN / 16; ++ks) {
        const int c0 = ks * 16 + l5 * 8;
        const float4 b0 = *(const float4*)(input + (size_t)i * FIN + c0);
        const float4 b1 = *(const float4*)(input + (size_t)i * FIN + c0 + 4);
        short8 bf;
        bf[0]=(short)f2bf(b0.x); bf[1]=(short)f2bf(b0.y); bf[2]=(short)f2bf(b0.z); bf[3]=(short)f2bf(b0.w);
        bf[4]=(short)f2bf(b1.x); bf[5]=(short)f2bf(b1.y); bf[6]=(short)f2bf(b1.z); bf[7]=(short)f2bf(b1.w);
        {
            const int kcol = l31 + 32 * (2 * mh + 0);
            const float4 a0 = *(const float4*)(W + (size_t)kcol * FIN + c0);
            const float4 a1 = *(const float4*)(W + (size_t)kcol * FIN + c0 + 4);
            short8 af;
            af[0]=(short)f2bf(a0.x); af[1]=(short)f2bf(a0.y); af[2]=(short)f2bf(a0.z); af[3]=(short)f2bf(a0.w);
            af[4]=(short)f2bf(a1.x); af[5]=(short)f2bf(a1.y); af[6]=(short)f2bf(a1.z); af[7]=(short)f2bf(a1.w);
            acc0 = __builtin_amdgcn_mfma_f32_32x32x16_bf16(af, bf, acc0, 0, 0, 0);
        }
        {
            const int kcol = l31 + 32 * (2 * mh + 1);
            const float4 a0 = *(const float4*)(W + (size_t)kcol * FIN + c0);
            const float4 a1 = *(const float4*)(W + (size_t)kcol * FIN + c0 + 4);
            short8 af;
            af[0]=(short)f2bf(a0.x); af[1]=(short)f2bf(a0.y); af[2]=(short)f2bf(a0.z); af[3]=(short)f2bf(a0.w);
            af[4]=(short)f2bf(a1.x); af[5]=(short)f2bf(a1.y); af[6]=(short)f2bf(a1.z); af[7]=(short)f2bf(a1.w);
            acc1 = __builtin_amdgcn_mfma_f32_32x32x16_bf16(af, bf, acc1, 0, 0, 0);
        }
    }
    float sacc = 0.f, tacc = 0.f;
    const int jt = bx * 2 + nt;                     // j-tile (32-wide)
    const int lane_half = 16 * (l31 >> 3);
    const int e4 = l31 & 7;
    #pragma unroll
    for (int m = 0; m < 2; ++m) {
        #pragma unroll
        for (int r = 0; r < 16; ++r) {
            const int kcol = 32 * (2 * mh + m) + 4 * l5 + (r & 3) + 8 * (r >> 2);
            const float hv = (m ? acc1[r] : acc0[r]) + Wb[kcol];
            const int lane4 = (kcol & 15) + lane_half;
            hT4[(size_t)(jt * 8 + (kcol >> 4)) * 512 + lane4 * 8 + e4] = f2bf(hv);
            sacc += hv * aw[kcol];
            tacc += hv * aw[FOUT + kcol];
        }
    }
    sacc += __shfl_xor(sacc, 32);
    tacc += __shfl_xor(tacc, 32);
    if (l < 32) { sred[w][l] = sacc; tred[w][l] = tacc; }
    __syncthreads();
    if (mh == 0 && l < 32) {
        s_out[i] = (sred[w][l] + sred[w + 1][l]) * LOG2E;
        t_out[i] = (tred[w][l] + tred[w + 1][l] + ab[0]) * LOG2E;
    }
}

// ---------------------------------------------------------------------------
// Pass B v3: 16x16x32 MFMA, wave owns 16 rows x 128 f. Per 64-j window the
// 16KB h-slice is staged into double-buffered LDS and SHARED by all 4 waves
// (cuts hT4 L2 traffic 4x; frag reads become conflict-free ds_read_b128).
// Global loads for window w+1 issue before compute of w (latency hidden);
// ds_write after; ONE barrier per window. Masks: per-lane register prefetch
// from bm3. t staged once in LDS. Denominator via 9th MFMA (all-ones A).
// ---------------------------------------------------------------------------
__global__ __launch_bounds__(256, 4)
void gat_pass_b(const u64* __restrict__ bm3, const unsigned short* __restrict__ hT4,
                const float* __restrict__ s_in, const float* __restrict__ t_in,
                float* __restrict__ numw, float* __restrict__ dpart) {
    __shared__ int4 hbuf[2][1024];           // 2 x 16KB
    __shared__ float tlds[JC];               // 4KB
    const int tid = threadIdx.x;
    const int wv = tid >> 6, l = tid & 63;
    const int li = l & 15;                   // i within wave tile
    const int kq = l >> 4;                   // k-quarter (0..3)
    const int i0 = blockIdx.x * 64;
    const int chunk = blockIdx.y;
    const int jb = chunk * JC;

    // stage t (coalesced, once)
    *(float4*)&tlds[tid * 4] = *(const float4*)(t_in + jb + tid * 4);

    // stage window 0 h-slice: 16KB contiguous, 4x 4KB coalesced instrs
    const int4* gsrc = (const int4*)hT4 + (size_t)chunk * 32 * 512;
    hbuf[0][tid]       = gsrc[tid];
    hbuf[0][tid + 256] = gsrc[tid + 256];
    hbuf[0][tid + 512] = gsrc[tid + 512];
    hbuf[0][tid + 768] = gsrc[tid + 768];

    const int lrow = wv * 16 + li;
    const float si = s_in[i0 + lrow];
    const u64* bmrow = bm3 + ((size_t)chunk * NN + i0 + lrow) * 16;
    u64 mcur = bmrow[0];
    __syncthreads();

    f32x4 acc0 = {}, acc1 = {}, acc2 = {}, acc3 = {};
    f32x4 acc4 = {}, acc5 = {}, acc6 = {}, acc7 = {};
    f32x4 accd = {};
    short8 ones;
    #pragma unroll
    for (int e = 0; e < 8; ++e) ones[e] = (short)0x3F80;   // bf16 1.0

    for (int w = 0; w < WPC; ++w) {
        const int buf = w & 1;
        // issue next window's global loads early (latency hides under compute)
        int4 g0, g1, g2, g3;
        u64 mnext = mcur;
        if (w + 1 < WPC) {
            const int4* gn = gsrc + (size_t)(w + 1) * 1024;
            g0 = gn[tid];
            g1 = gn[tid + 256];
            g2 = gn[tid + 512];
            g3 = gn[tid + 768];
            mnext = bmrow[w + 1];
        }
        // ---- compute window w from LDS ----
        #pragma unroll
        for (int kk = 0; kk < 2; ++kk) {
            const int4* hb = &hbuf[buf][kk * 512];
            const short8 af0 = *(const short8*)&hb[0 * 64 + l];
            const short8 af1 = *(const short8*)&hb[1 * 64 + l];
            const short8 af2 = *(const short8*)&hb[2 * 64 + l];
            const short8 af3 = *(const short8*)&hb[3 * 64 + l];
            const short8 af4 = *(const short8*)&hb[4 * 64 + l];
            const short8 af5 = *(const short8*)&hb[5 * 64 + l];
            const short8 af6 = *(const short8*)&hb[6 * 64 + l];
            const short8 af7 = *(const short8*)&hb[7 * 64 + l];
            const int tix = w * 64 + kk * 32 + kq * 8;
            const float4 t0 = *(const float4*)&tlds[tix];
            const float4 t1 = *(const float4*)&tlds[tix + 4];
            const unsigned mk = (unsigned)(mcur >> (kk * 32 + kq * 8)) & 0xffu;

            float x, p0, p1, p2, p3, p4, p5, p6, p7;
            x = si + t0.x; x = fmaxf(x, 0.2f * x); p0 = exp2f(x);
            p0 = (mk & 1u)   ? p0 : 0.f;
            x = si + t0.y; x = fmaxf(x, 0.2f * x); p1 = exp2f(x);
            p1 = (mk & 2u)   ? p1 : 0.f;
            x = si + t0.z; x = fmaxf(x, 0.2f * x); p2 = exp2f(x);
            p2 = (mk & 4u)   ? p2 : 0.f;
            x = si + t0.w; x = fmaxf(x, 0.2f * x); p3 = exp2f(x);
            p3 = (mk & 8u)   ? p3 : 0.f;
            x = si + t1.x; x = fmaxf(x, 0.2f * x); p4 = exp2f(x);
            p4 = (mk & 16u)  ? p4 : 0.f;
            x = si + t1.y; x = fmaxf(x, 0.2f * x); p5 = exp2f(x);
            p5 = (mk & 32u)  ? p5 : 0.f;
            x = si + t1.z; x = fmaxf(x, 0.2f * x); p6 = exp2f(x);
            p6 = (mk & 64u)  ? p6 : 0.f;
            x = si + t1.w; x = fmaxf(x, 0.2f * x); p7 = exp2f(x);
            p7 = (mk & 128u) ? p7 : 0.f;

            union { int4 i4; short8 s8; } bu;
            bu.i4.x = (int)cvtpk(p0, p1);
            bu.i4.y = (int)cvtpk(p2, p3);
            bu.i4.z = (int)cvtpk(p4, p5);
            bu.i4.w = (int)cvtpk(p6, p7);
            const short8 bf = bu.s8;

            acc0 = __builtin_amdgcn_mfma_f32_16x16x32_bf16(af0, bf, acc0, 0, 0, 0);
            acc1 = __builtin_amdgcn_mfma_f32_16x16x32_bf16(af1, bf, acc1, 0, 0, 0);
            acc2 = __builtin_amdgcn_mfma_f32_16x16x32_bf16(af2, bf, acc2, 0, 0, 0);
            acc3 = __builtin_amdgcn_mfma_f32_16x16x32_bf16(af3, bf, acc3, 0, 0, 0);
            acc4 = __builtin_amdgcn_mfma_f32_16x16x32_bf16(af4, bf, acc4, 0, 0, 0);
            acc5 = __builtin_amdgcn_mfma_f32_16x16x32_bf16(af5, bf, acc5, 0, 0, 0);
            acc6 = __builtin_amdgcn_mfma_f32_16x16x32_bf16(af6, bf, acc6, 0, 0, 0);
            acc7 = __builtin_amdgcn_mfma_f32_16x16x32_bf16(af7, bf, acc7, 0, 0, 0);
            accd = __builtin_amdgcn_mfma_f32_16x16x32_bf16(ones, bf, accd, 0, 0, 0);
        }
        // ---- write next window into the other buffer ----
        if (w + 1 < WPC) {
            hbuf[buf ^ 1][tid]       = g0;
            hbuf[buf ^ 1][tid + 256] = g1;
            hbuf[buf ^ 1][tid + 512] = g2;
            hbuf[buf ^ 1][tid + 768] = g3;
        }
        mcur = mnext;
        __syncthreads();
    }

    // ---- epilogue: direct coalesced stores (no reduction) ----
    float* nb = numw + (size_t)chunk * FOUT * NN;
    const int irow = i0 + lrow;
    #pragma unroll
    for (int r = 0; r < 4; ++r) {
        const int fr = kq * 4 + r;
        nb[(size_t)(fr      ) * NN + irow] = acc0[r];
        nb[(size_t)(fr + 16 ) * NN + irow] = acc1[r];
        nb[(size_t)(fr + 32 ) * NN + irow] = acc2[r];
        nb[(size_t)(fr + 48 ) * NN + irow] = acc3[r];
        nb[(size_t)(fr + 64 ) * NN + irow] = acc4[r];
        nb[(size_t)(fr + 80 ) * NN + irow] = acc5[r];
        nb[(size_t)(fr + 96 ) * NN + irow] = acc6[r];
        nb[(size_t)(fr + 112) * NN + irow] = acc7[r];
    }
    if (l < 16) dpart[(size_t)chunk * NN + i0 + wv * 16 + l] = accd[0];
}

// ---------------------------------------------------------------------------
// Pass C: out[i][f] = elu( sum_c numw[c][f][i] / sum_c dpart[c][i] )
// ---------------------------------------------------------------------------
__global__ __launch_bounds__(256)
void gat_reduce(const float* __restrict__ numw, const float* __restrict__ dpart,
                float* __restrict__ out, int nchunk) {
    __shared__ float tile[FOUT * 33];
    __shared__ float dent[32];
    const int t = threadIdx.x;
    const int i0 = blockIdx.x * 32;
    if (t < 32) {
        float d = 0.f;
        for (int c = 0; c < nchunk; ++c) d += dpart[(size_t)c * NN + i0 + t];
        dent[t] = d;
    }
    __syncthreads();
    #pragma unroll
    for (int e = 0; e < 4; ++e) {
        const int f = e * 32 + (t >> 3);
        const int io = (t & 7) * 4;
        float4 s = {0.f, 0.f, 0.f, 0.f};
        for (int c = 0; c < nchunk; ++c) {
            const float4 v = *(const float4*)(numw + ((size_t)c * FOUT + f) * NN + i0 + io);
            s.x += v.x; s.y += v.y; s.z += v.z; s.w += v.w;
        }
        float v;
        v = s.x / dent[io + 0]; tile[f * 33 + io + 0] = (v > 0.f) ? v : expm1f(v);
        v = s.y / dent[io + 1]; tile[f * 33 + io + 1] = (v > 0.f) ? v : expm1f(v);
        v = s.z / dent[io + 2]; tile[f * 33 + io + 2] = (v > 0.f) ? v : expm1f(v);
        v = s.w / dent[io + 3]; tile[f * 33 + io + 3] = (v > 0.f) ? v : expm1f(v);
    }
    __syncthreads();
    #pragma unroll
    for (int e = 0; e < 4; ++e) {
        const int row = (t >> 5) * 4 + e;
        const int fo = (t & 31) * 4;
        const float4 v = { tile[(fo + 0) * 33 + row], tile[(fo + 1) * 33 + row],
                           tile[(fo + 2) * 33 + row], tile[(fo + 3) * 33 + row] };
        *(float4*)(out + (size_t)(i0 + row) * FOUT + fo) = v;
    }
}

// ---------------------------------------------------------------------------
extern "C" void kernel_launch(void* const* d_in, const int* in_sizes, int n_in,
                              void* d_out, int out_size, void* d_ws, size_t ws_size,
                              hipStream_t stream) {
    const float* input = (const float*)d_in[0];
    const int*   adj   = (const int*)d_in[1];
    const float* Ww    = (const float*)d_in[2];
    const float* Wb    = (const float*)d_in[3];
    const float* aw    = (const float*)d_in[4];
    const float* ab    = (const float*)d_in[5];
    float* out = (float*)d_out;

    char* ws = (char*)d_ws;
    unsigned short* hT4 = (unsigned short*)ws;               // 2 MB
    float* s_buf = (float*)(ws + (size_t)FOUT * NN * 2);     // 32 KB
    float* t_buf = s_buf + NN;                               // 32 KB
    float* dpart = t_buf + NN;                               // NCH*32 KB
    float* numw = dpart + (size_t)NCH * NN;                  // NCH*4 MB
    u64* bm3 = (u64*)(numw + (size_t)NCH * NN * FOUT);       // 8 MB

    gat_stage<<<dim3(128 + NN / 2), 256, 0, stream>>>(input, adj, Ww, Wb, aw, ab,
                                                      hT4, s_buf, t_buf, bm3);
    gat_pass_b<<<dim3(NN / 64, NCH), 256, 0, stream>>>(bm3, hT4, s_buf, t_buf, numw, dpart);
    gat_reduce<<<dim3(NN / 32), 256, 0, stream>>>(numw, dpart, out, NCH);
}